// Round 1
// baseline (682.799 us; speedup 1.0000x reference)
//
#include <hip/hip_runtime.h>

typedef unsigned short u16;
typedef unsigned int u32;
typedef __attribute__((ext_vector_type(4))) float f32x4;
typedef __attribute__((ext_vector_type(8))) short bf16x8;
typedef __attribute__((ext_vector_type(2))) unsigned int u32x2;

#define S_LEN 2048
#define NHEAD 32
#define HDD 128
#define HID 4096
#define N_QKV 12288
#define KDIM 4096

__device__ __forceinline__ u16 f2bf(float f) {
  u32 u = __builtin_bit_cast(u32, f);
  u = (u + 0x7FFFu + ((u >> 16) & 1u)) >> 16;
  return (u16)u;
}
__device__ __forceinline__ float bf2f(u16 h) {
  u32 u = ((u32)h) << 16;
  return __builtin_bit_cast(float, u);
}

__device__ __forceinline__ void gl2lds16(const void* g, void* l) {
  __builtin_amdgcn_global_load_lds(
      (const __attribute__((address_space(1))) u32*)g,
      (__attribute__((address_space(3))) u32*)l, 16, 0, 0);
}

// ---------------- fp32 -> bf16 conversion ----------------
__global__ __launch_bounds__(256) void cvt_kernel(const float* __restrict__ in,
                                                  u16* __restrict__ out, int n4) {
  int i = blockIdx.x * blockDim.x + threadIdx.x;
  int st = gridDim.x * blockDim.x;
  for (; i < n4; i += st) {
    float4 v = ((const float4*)in)[i];
    u32x2 o;
    o.x = (u32)f2bf(v.x) | ((u32)f2bf(v.y) << 16);
    o.y = (u32)f2bf(v.z) | ((u32)f2bf(v.w) << 16);
    ((u32x2*)out)[i] = o;
  }
}

// ---------------- RoPE tables: cos/sin [S][32] ----------------
__global__ __launch_bounds__(256) void tables_kernel(float* __restrict__ cos_t,
                                                     float* __restrict__ sin_t) {
  int idx = blockIdx.x * blockDim.x + threadIdx.x;
  if (idx >= S_LEN * 32) return;
  int s = idx >> 5, i = idx & 31;
  // inv_freq = 10000^(-i/32) = exp(-i * ln(10000)/32)
  float invf = expf(-0.28782313662425572f * (float)i);
  float a = (float)s * invf;
  cos_t[idx] = cosf(a);
  sin_t[idx] = sinf(a);
}

// ---------------- 2D RoPE in-place on q/k (head-major [h][s][128]) -------
__global__ __launch_bounds__(256) void rope_kernel(u16* __restrict__ qb, u16* __restrict__ kb,
                                                   const int* __restrict__ pid,
                                                   const float* __restrict__ cos_t,
                                                   const float* __restrict__ sin_t) {
  int idx = blockIdx.x * blockDim.x + threadIdx.x;
  const int total = 2 * NHEAD * S_LEN * 64;  // (qk, h, s, half, i<32) = 2^23
  int st = gridDim.x * blockDim.x;
  for (; idx < total; idx += st) {
    int i = idx & 31;
    int half = (idx >> 5) & 1;
    int s = (idx >> 6) & (S_LEN - 1);
    int h = (idx >> 17) & (NHEAD - 1);
    int qk = idx >> 22;
    int p = pid[half * S_LEN + s];  // half0: pos, half1: block_pos
    float c = cos_t[p * 32 + i], sn = sin_t[p * 32 + i];
    u16* buf = qk ? kb : qb;
    int base = (h * S_LEN + s) * HDD + half * 64 + i;
    float x1 = bf2f(buf[base]), x2 = bf2f(buf[base + 32]);
    float o1 = x1 * c - x2 * sn;
    float o2 = x2 * c + x1 * sn;
    float sc = qk ? 1.0f : 0.08838834764831845f;  // q pre-scaled by 1/sqrt(128)
    buf[base] = f2bf(o1 * sc);
    buf[base + 32] = f2bf(o2 * sc);
  }
}

// ---------------- 128x128 bf16 GEMM (m97 structure), C = A * B^T + bias --
// A: [M][K] bf16 row-major. B: [N][K] bf16 row-major (K contiguous).
// EPI 0: scatter into q/k/v head-major bf16 buffers. EPI 1: fp32 out.
template <int EPI>
__global__ __launch_bounds__(256) void gemm128(const u16* __restrict__ A,
                                               const u16* __restrict__ B,
                                               const float* __restrict__ bias, int N, int K,
                                               u16* __restrict__ qb, u16* __restrict__ kb,
                                               u16* __restrict__ vb, float* __restrict__ outf) {
  __shared__ __align__(16) u16 Ash[128 * 32];
  __shared__ __align__(16) u16 Bsh[128 * 32];
  int tid = threadIdx.x;
  int lane = tid & 63, w = tid >> 6;
  int lane15 = lane & 15, g = lane >> 4;
  int wm = w >> 1, wn = w & 1;
  int bm = blockIdx.y * 128, bn = blockIdx.x * 128;

  f32x4 acc[4][4];
  f32x4 z4 = {0.f, 0.f, 0.f, 0.f};
#pragma unroll
  for (int mi = 0; mi < 4; ++mi)
#pragma unroll
    for (int ni = 0; ni < 4; ++ni) acc[mi][ni] = z4;

  // staging: wave w loads rows [w*32, w*32+32) of each tile; 2 x 1KB instrs each
  const u16* Arow = A + (size_t)(bm + w * 32 + (lane >> 2)) * K + (lane & 3) * 8;
  const u16* Brow = B + (size_t)(bn + w * 32 + (lane >> 2)) * K + (lane & 3) * 8;
  u16* AshW = Ash + (w * 32) * 32;
  u16* BshW = Bsh + (w * 32) * 32;

  int nk = K >> 5;
  for (int kt = 0; kt < nk; ++kt) {
    __syncthreads();
    const u16* ag = Arow + kt * 32;
    const u16* bg = Brow + kt * 32;
    gl2lds16(ag, AshW);
    gl2lds16(ag + 16 * (size_t)K, AshW + 16 * 32);
    gl2lds16(bg, BshW);
    gl2lds16(bg + 16 * (size_t)K, BshW + 16 * 32);
    asm volatile("s_waitcnt vmcnt(0)" ::: "memory");
    __syncthreads();
    bf16x8 a[4], b[4];
#pragma unroll
    for (int mi = 0; mi < 4; ++mi)
      a[mi] = *(const bf16x8*)(Ash + (wm * 64 + mi * 16 + lane15) * 32 + g * 8);
#pragma unroll
    for (int ni = 0; ni < 4; ++ni)
      b[ni] = *(const bf16x8*)(Bsh + (wn * 64 + ni * 16 + lane15) * 32 + g * 8);
#pragma unroll
    for (int mi = 0; mi < 4; ++mi)
#pragma unroll
      for (int ni = 0; ni < 4; ++ni)
        acc[mi][ni] = __builtin_amdgcn_mfma_f32_16x16x32_bf16(a[mi], b[ni], acc[mi][ni], 0, 0, 0);
  }

  // epilogue: D layout: row(M) = 4*g + r, col(N) = lane15
#pragma unroll
  for (int ni = 0; ni < 4; ++ni) {
    int n = bn + wn * 64 + ni * 16 + lane15;
    float bv = bias[n];
    if (EPI == 0) {
      int head = n / 384;
      int rem = n - head * 384;
      int part = rem >> 7;
      int d = rem & 127;
      u16* dst = (part == 0 ? qb : (part == 1 ? kb : vb)) + (size_t)head * S_LEN * HDD + d;
#pragma unroll
      for (int mi = 0; mi < 4; ++mi) {
        int m0 = bm + wm * 64 + mi * 16 + 4 * g;
#pragma unroll
        for (int r = 0; r < 4; ++r) dst[(size_t)(m0 + r) * HDD] = f2bf(acc[mi][ni][r] + bv);
      }
    } else {
#pragma unroll
      for (int mi = 0; mi < 4; ++mi) {
        int m0 = bm + wm * 64 + mi * 16 + 4 * g;
#pragma unroll
        for (int r = 0; r < 4; ++r) outf[(size_t)(m0 + r) * N + n] = acc[mi][ni][r] + bv;
      }
    }
  }
}

// ---------------- flash attention -----------------------------------------
// grid (S/64, NHEAD), 256 threads. Wave w owns q rows [qbase+16w, +16).
// Swapped S^T = K * Q^T so each lane's S column is one q-row.
__global__ __launch_bounds__(256) void attn_kernel(const u16* __restrict__ qb,
                                                   const u16* __restrict__ kb,
                                                   const u16* __restrict__ vb,
                                                   u16* __restrict__ ctx) {
  __shared__ __align__(16) u16 Ksh[32 * 136];   // [k][d] padded stride 136
  __shared__ __align__(16) u16 Vsh[128 * 32];   // [d][k], 16B-block xor swizzle
  __shared__ __align__(16) u16 Pt[4][16 * 40];  // per-wave P^T [q][k] stride 40

  int tid = threadIdx.x;
  int lane = tid & 63, w = tid >> 6;
  int lane15 = lane & 15, g = lane >> 4;
  int h = blockIdx.y;
  int qbase = blockIdx.x * 64;
  int qrow = qbase + w * 16 + lane15;  // this lane's q-row (S^T column)

  // Q fragments in registers: qf[d0] = Q[qrow][32*d0 + 8g .. +7]
  bf16x8 qf[4];
  const u16* qptr = qb + ((size_t)h * S_LEN + qrow) * HDD + g * 8;
#pragma unroll
  for (int d0 = 0; d0 < 4; ++d0) qf[d0] = *(const bf16x8*)(qptr + d0 * 32);

  f32x4 pv[8];
  f32x4 z4 = {0.f, 0.f, 0.f, 0.f};
#pragma unroll
  for (int db = 0; db < 8; ++db) pv[db] = z4;
  float m_run = -1e30f, l_run = 0.0f;

  const u16* kp = kb + (size_t)h * S_LEN * HDD;
  const u16* vp = vb + (size_t)h * S_LEN * HDD;
  int krow = tid >> 3, kc = (tid & 7) * 16;       // K staging map
  int vk = tid & 31, vd0 = (tid >> 5) * 16;       // V staging map
  int ntiles = (qbase >> 5) + 2;

  for (int t = 0; t < ntiles; ++t) {
    int kb0 = t * 32;
    __syncthreads();
    {  // stage K [32][128] -> Ksh padded
      const bf16x8* src = (const bf16x8*)(kp + (size_t)(kb0 + krow) * HDD + kc);
      bf16x8 x0 = src[0], x1 = src[1];
      *(bf16x8*)(Ksh + krow * 136 + kc) = x0;
      *(bf16x8*)(Ksh + krow * 136 + kc + 8) = x1;
      // stage V transposed with block swizzle: Vsh[d][k] at d*32 + ((k>>3)^(d&3))*8 + (k&7)
      const bf16x8* vsrc = (const bf16x8*)(vp + (size_t)(kb0 + vk) * HDD + vd0);
      bf16x8 v0 = vsrc[0], v1 = vsrc[1];
#pragma unroll
      for (int j = 0; j < 8; ++j) {
        int d = vd0 + j;
        Vsh[d * 32 + (((vk >> 3) ^ (d & 3)) << 3) + (vk & 7)] = (u16)v0[j];
        int d2 = vd0 + 8 + j;
        Vsh[d2 * 32 + (((vk >> 3) ^ (d2 & 3)) << 3) + (vk & 7)] = (u16)v1[j];
      }
    }
    __syncthreads();

    // S^T tile: rows k (2 mfmas of 16), cols q
    f32x4 sa0 = z4, sa1 = z4;
#pragma unroll
    for (int d0 = 0; d0 < 4; ++d0) {
      bf16x8 k0 = *(const bf16x8*)(Ksh + lane15 * 136 + d0 * 32 + g * 8);
      bf16x8 k1 = *(const bf16x8*)(Ksh + (16 + lane15) * 136 + d0 * 32 + g * 8);
      sa0 = __builtin_amdgcn_mfma_f32_16x16x32_bf16(k0, qf[d0], sa0, 0, 0, 0);
      sa1 = __builtin_amdgcn_mfma_f32_16x16x32_bf16(k1, qf[d0], sa1, 0, 0, 0);
    }
    // per-lane S values: k = kb0 + tt*16 + 4g + r, q = qrow (causal mask)
    float s[8];
#pragma unroll
    for (int r = 0; r < 4; ++r) {
      int kg0 = kb0 + 4 * g + r;
      int kg1 = kb0 + 16 + 4 * g + r;
      s[r] = (kg0 > qrow) ? -1e30f : sa0[r];
      s[4 + r] = (kg1 > qrow) ? -1e30f : sa1[r];
    }
    float mx = s[0];
#pragma unroll
    for (int i = 1; i < 8; ++i) mx = fmaxf(mx, s[i]);
    mx = fmaxf(mx, __shfl_xor(mx, 16));
    mx = fmaxf(mx, __shfl_xor(mx, 32));
    float mnew = fmaxf(m_run, mx);
    float fac = exp2f((m_run - mnew) * 1.4426950408889634f);
    float p[8], psum = 0.f;
#pragma unroll
    for (int i = 0; i < 8; ++i) {
      p[i] = exp2f((s[i] - mnew) * 1.4426950408889634f);
      psum += p[i];
    }
    psum += __shfl_xor(psum, 16);
    psum += __shfl_xor(psum, 32);
    l_run = l_run * fac + psum;
    m_run = mnew;
#pragma unroll
    for (int db = 0; db < 8; ++db) pv[db] *= fac;

    // P^T -> LDS: lane holds k = 4g..4g+3 (t0) and 16+4g..+3 (t1) for col q=lane15
    u32 w0 = (u32)f2bf(p[0]) | ((u32)f2bf(p[1]) << 16);
    u32 w1 = (u32)f2bf(p[2]) | ((u32)f2bf(p[3]) << 16);
    u32 w2 = (u32)f2bf(p[4]) | ((u32)f2bf(p[5]) << 16);
    u32 w3 = (u32)f2bf(p[6]) | ((u32)f2bf(p[7]) << 16);
    u32x2 pa, pb;
    pa.x = w0; pa.y = w1; pb.x = w2; pb.y = w3;
    *(u32x2*)(&Pt[w][lane15 * 40 + 4 * g]) = pa;
    *(u32x2*)(&Pt[w][lane15 * 40 + 16 + 4 * g]) = pb;
    asm volatile("s_waitcnt lgkmcnt(0)" ::: "memory");
    bf16x8 pfrag = *(const bf16x8*)(&Pt[w][lane15 * 40 + 8 * g]);  // B[k=8g..8g+7][q]

    // PV: C^T[d][q] += V^T[d][k] * P^T[k][q]
#pragma unroll
    for (int db = 0; db < 8; ++db) {
      int d = db * 16 + lane15;
      bf16x8 vf = *(const bf16x8*)(Vsh + d * 32 + ((g ^ (d & 3)) << 3));
      pv[db] = __builtin_amdgcn_mfma_f32_16x16x32_bf16(vf, pfrag, pv[db], 0, 0, 0);
    }
  }

  float inv = 1.0f / l_run;
#pragma unroll
  for (int db = 0; db < 8; ++db) {
    ushort4 o;
    o.x = f2bf(pv[db][0] * inv);
    o.y = f2bf(pv[db][1] * inv);
    o.z = f2bf(pv[db][2] * inv);
    o.w = f2bf(pv[db][3] * inv);
    *(ushort4*)(ctx + (size_t)qrow * HID + h * HDD + db * 16 + 4 * g) = o;
  }
}

// ---------------- launcher -------------------------------------------------
extern "C" void kernel_launch(void* const* d_in, const int* in_sizes, int n_in,
                              void* d_out, int out_size, void* d_ws, size_t ws_size,
                              hipStream_t stream) {
  const float* hidden = (const float*)d_in[0];
  const int* pid = (const int*)d_in[1];
  // d_in[2] attention_mask: always causal triu -> handled analytically
  const float* wqkv = (const float*)d_in[3];
  const float* bqkv = (const float*)d_in[4];
  const float* wdense = (const float*)d_in[5];
  const float* bdense = (const float*)d_in[6];
  // d_in[7] layer_id: coeff cancels in softmax
  float* out = (float*)d_out;

  char* ws = (char*)d_ws;
  u16* W1 = (u16*)ws;                          // 12288*4096 bf16 = 100663296 B
  u16* W2 = (u16*)(ws + 100663296);            // 4096*4096  bf16 =  33554432 B
  u16* X = (u16*)(ws + 134217728);             // 2048*4096  bf16 =  16777216 B
  u16* qb = (u16*)(ws + 150994944);            // 32*2048*128 bf16
  u16* kbuf = (u16*)(ws + 167772160);
  u16* vbuf = (u16*)(ws + 184549376);
  u16* ctx = (u16*)(ws + 201326592);           // 2048*4096 bf16
  float* cos_t = (float*)(ws + 218103808);     // 2048*32 f32
  float* sin_t = (float*)(ws + 218365952);

  cvt_kernel<<<dim3(2048), dim3(256), 0, stream>>>(wqkv, W1, N_QKV * KDIM / 4);
  cvt_kernel<<<dim3(1024), dim3(256), 0, stream>>>(wdense, W2, HID * KDIM / 4);
  cvt_kernel<<<dim3(512), dim3(256), 0, stream>>>(hidden, X, S_LEN * HID / 4);
  tables_kernel<<<dim3(256), dim3(256), 0, stream>>>(cos_t, sin_t);

  gemm128<0><<<dim3(N_QKV / 128, S_LEN / 128), dim3(256), 0, stream>>>(
      X, W1, bqkv, N_QKV, KDIM, qb, kbuf, vbuf, nullptr);

  rope_kernel<<<dim3(4096), dim3(256), 0, stream>>>(qb, kbuf, pid, cos_t, sin_t);

  attn_kernel<<<dim3(S_LEN / 64, NHEAD), dim3(256), 0, stream>>>(qb, kbuf, vbuf, ctx);

  gemm128<1><<<dim3(HID / 128, S_LEN / 128), dim3(256), 0, stream>>>(
      ctx, W2, bdense, HID, KDIM, nullptr, nullptr, nullptr, out);
}

// Round 2
// 645.967 us; speedup vs baseline: 1.0570x; 1.0570x over previous
//
#include <hip/hip_runtime.h>

typedef unsigned short u16;
typedef unsigned int u32;
typedef __attribute__((ext_vector_type(4))) float f32x4;
typedef __attribute__((ext_vector_type(8))) short bf16x8;
typedef __attribute__((ext_vector_type(2))) unsigned int u32x2;

#define S_LEN 2048
#define NHEAD 32
#define HDD 128
#define HID 4096
#define N_QKV 12288
#define KDIM 4096
#define NT (KDIM / 32)  // 128 K-tiles of BK=32

__device__ __forceinline__ u16 f2bf(float f) {
  u32 u = __builtin_bit_cast(u32, f);
  u = (u + 0x7FFFu + ((u >> 16) & 1u)) >> 16;
  return (u16)u;
}
__device__ __forceinline__ float bf2f(u16 h) {
  u32 u = ((u32)h) << 16;
  return __builtin_bit_cast(float, u);
}

__device__ __forceinline__ void gl2lds16(const void* g, void* l) {
  __builtin_amdgcn_global_load_lds(
      (const __attribute__((address_space(1))) u32*)g,
      (__attribute__((address_space(3))) u32*)l, 16, 0, 0);
}

// ---------------- fp32 -> bf16 conversion ----------------
__global__ __launch_bounds__(256) void cvt_kernel(const float* __restrict__ in,
                                                  u16* __restrict__ out, int n4) {
  int i = blockIdx.x * blockDim.x + threadIdx.x;
  int st = gridDim.x * blockDim.x;
  for (; i < n4; i += st) {
    float4 v = ((const float4*)in)[i];
    u32x2 o;
    o.x = (u32)f2bf(v.x) | ((u32)f2bf(v.y) << 16);
    o.y = (u32)f2bf(v.z) | ((u32)f2bf(v.w) << 16);
    ((u32x2*)out)[i] = o;
  }
}

// ---------------- RoPE tables: cos/sin [S][32] ----------------
__global__ __launch_bounds__(256) void tables_kernel(float* __restrict__ cos_t,
                                                     float* __restrict__ sin_t) {
  int idx = blockIdx.x * blockDim.x + threadIdx.x;
  if (idx >= S_LEN * 32) return;
  int s = idx >> 5, i = idx & 31;
  float invf = expf(-0.28782313662425572f * (float)i);
  float a = (float)s * invf;
  cos_t[idx] = cosf(a);
  sin_t[idx] = sinf(a);
}

// ---------------- 2D RoPE in-place on q/k (head-major [h][s][128]) -------
__global__ __launch_bounds__(256) void rope_kernel(u16* __restrict__ qb, u16* __restrict__ kb,
                                                   const int* __restrict__ pid,
                                                   const float* __restrict__ cos_t,
                                                   const float* __restrict__ sin_t) {
  int idx = blockIdx.x * blockDim.x + threadIdx.x;
  const int total = 2 * NHEAD * S_LEN * 64;
  int st = gridDim.x * blockDim.x;
  for (; idx < total; idx += st) {
    int i = idx & 31;
    int half = (idx >> 5) & 1;
    int s = (idx >> 6) & (S_LEN - 1);
    int h = (idx >> 17) & (NHEAD - 1);
    int qk = idx >> 22;
    int p = pid[half * S_LEN + s];
    float c = cos_t[p * 32 + i], sn = sin_t[p * 32 + i];
    u16* buf = qk ? kb : qb;
    int base = (h * S_LEN + s) * HDD + half * 64 + i;
    float x1 = bf2f(buf[base]), x2 = bf2f(buf[base + 32]);
    float o1 = x1 * c - x2 * sn;
    float o2 = x2 * c + x1 * sn;
    float sc = qk ? 1.0f : 0.08838834764831845f;
    buf[base] = f2bf(o1 * sc);
    buf[base + 32] = f2bf(o2 * sc);
  }
}

// ---------------- 256x128 bf16 GEMM, ring-3 LDS, counted vmcnt ------------
// C = A * B^T + bias.  A:[M][K] bf16, B:[N][K] bf16 (K contiguous).
// 512 threads = 8 waves (WM=4 x WN=2), per-wave 64x64 output, BK=32.
// Prefetch distance 2 K-tiles; per-iter: issue 3 global_load_lds (tile kt+2),
// s_waitcnt vmcnt(6) (tile kt landed, 2 tiles stay in flight), barrier,
// ds_read frags, setprio(1) 16xMFMA setprio(0), barrier.
template <int EPI>
__global__ __launch_bounds__(512, 2) void gemm256(const u16* __restrict__ A,
                                                  const u16* __restrict__ B,
                                                  const float* __restrict__ bias, int N,
                                                  u16* __restrict__ qb, u16* __restrict__ kb,
                                                  u16* __restrict__ vb, float* __restrict__ outf) {
  __shared__ __align__(16) u16 Ash[3][256 * 32];  // 3 x 16 KB
  __shared__ __align__(16) u16 Bsh[3][128 * 32];  // 3 x 8 KB

  const int tid = threadIdx.x;
  const int lane = tid & 63, w = tid >> 6;
  const int l15 = lane & 15, g = lane >> 4;
  const int wm = w >> 1, wn = w & 1;
  const int bm = blockIdx.x * 256, bn = blockIdx.y * 128;

  f32x4 acc[4][4];
  f32x4 z4 = {0.f, 0.f, 0.f, 0.f};
#pragma unroll
  for (int mi = 0; mi < 4; ++mi)
#pragma unroll
    for (int ni = 0; ni < 4; ++ni) acc[mi][ni] = z4;

  // staging map: thread t writes 16B at byte t*16 of each 8KB unit:
  //   row r = t>>2 (0..127), 16B-block c = t&3. Global source matches linearly.
  const size_t Kb = (size_t)KDIM * 2;  // row stride in bytes
  const int r = tid >> 2, c = tid & 3;
  const char* pA0 = (const char*)A + (size_t)(bm + r) * Kb + (size_t)(c * 16);
  const char* pA1 = pA0 + (size_t)128 * Kb;
  const char* pB = (const char*)B + (size_t)(bn + r) * Kb + (size_t)(c * 16);

#define ISSUE(slot, t64)                                              \
  {                                                                   \
    gl2lds16(pA0 + (size_t)(t64) * 64, Ash[slot] + w * 512);          \
    gl2lds16(pA1 + (size_t)(t64) * 64, Ash[slot] + 4096 + w * 512);   \
    gl2lds16(pB + (size_t)(t64) * 64, Bsh[slot] + w * 512);           \
  }

  ISSUE(0, 0);
  ISSUE(1, 1);
  int sw = 2, sr = 0;
  for (int kt = 0; kt < NT; ++kt) {
    if (kt < NT - 2) {
      ISSUE(sw, kt + 2);
      asm volatile("s_waitcnt vmcnt(6)" ::: "memory");
    } else if (kt == NT - 2) {
      asm volatile("s_waitcnt vmcnt(3)" ::: "memory");
    } else {
      asm volatile("s_waitcnt vmcnt(0)" ::: "memory");
    }
    __builtin_amdgcn_s_barrier();
    asm volatile("" ::: "memory");

    const u16* As = Ash[sr];
    const u16* Bs = Bsh[sr];
    bf16x8 a[4], b[4];
#pragma unroll
    for (int mi = 0; mi < 4; ++mi)
      a[mi] = *(const bf16x8*)(As + (wm * 64 + mi * 16 + l15) * 32 + g * 8);
#pragma unroll
    for (int ni = 0; ni < 4; ++ni)
      b[ni] = *(const bf16x8*)(Bs + (wn * 64 + ni * 16 + l15) * 32 + g * 8);

    __builtin_amdgcn_s_setprio(1);
#pragma unroll
    for (int mi = 0; mi < 4; ++mi)
#pragma unroll
      for (int ni = 0; ni < 4; ++ni)
        acc[mi][ni] = __builtin_amdgcn_mfma_f32_16x16x32_bf16(a[mi], b[ni], acc[mi][ni], 0, 0, 0);
    __builtin_amdgcn_s_setprio(0);

    asm volatile("" ::: "memory");
    __builtin_amdgcn_s_barrier();
    asm volatile("" ::: "memory");
    sw = (sw + 1 == 3) ? 0 : sw + 1;
    sr = (sr + 1 == 3) ? 0 : sr + 1;
  }
#undef ISSUE

  // epilogue: D row(M) = 4*g + reg, col(N) = l15 (verified mapping)
#pragma unroll
  for (int ni = 0; ni < 4; ++ni) {
    int n = bn + wn * 64 + ni * 16 + l15;
    float bv = bias[n];
    if (EPI == 0) {
      int head = n / 384;
      int rem = n - head * 384;
      int part = rem >> 7;
      int d = rem & 127;
      u16* dst = (part == 0 ? qb : (part == 1 ? kb : vb)) + (size_t)head * S_LEN * HDD + d;
#pragma unroll
      for (int mi = 0; mi < 4; ++mi) {
        int m0 = bm + wm * 64 + mi * 16 + 4 * g;
#pragma unroll
        for (int rr = 0; rr < 4; ++rr) dst[(size_t)(m0 + rr) * HDD] = f2bf(acc[mi][ni][rr] + bv);
      }
    } else {
#pragma unroll
      for (int mi = 0; mi < 4; ++mi) {
        int m0 = bm + wm * 64 + mi * 16 + 4 * g;
#pragma unroll
        for (int rr = 0; rr < 4; ++rr) outf[(size_t)(m0 + rr) * N + n] = acc[mi][ni][rr] + bv;
      }
    }
  }
}

// ---------------- flash attention -----------------------------------------
__global__ __launch_bounds__(256) void attn_kernel(const u16* __restrict__ qb,
                                                   const u16* __restrict__ kb,
                                                   const u16* __restrict__ vb,
                                                   u16* __restrict__ ctx) {
  __shared__ __align__(16) u16 Ksh[32 * 136];
  __shared__ __align__(16) u16 Vsh[128 * 32];
  __shared__ __align__(16) u16 Pt[4][16 * 40];

  int tid = threadIdx.x;
  int lane = tid & 63, w = tid >> 6;
  int lane15 = lane & 15, g = lane >> 4;
  int h = blockIdx.y;
  int qbase = blockIdx.x * 64;
  int qrow = qbase + w * 16 + lane15;

  bf16x8 qf[4];
  const u16* qptr = qb + ((size_t)h * S_LEN + qrow) * HDD + g * 8;
#pragma unroll
  for (int d0 = 0; d0 < 4; ++d0) qf[d0] = *(const bf16x8*)(qptr + d0 * 32);

  f32x4 pv[8];
  f32x4 z4 = {0.f, 0.f, 0.f, 0.f};
#pragma unroll
  for (int db = 0; db < 8; ++db) pv[db] = z4;
  float m_run = -1e30f, l_run = 0.0f;

  const u16* kp = kb + (size_t)h * S_LEN * HDD;
  const u16* vp = vb + (size_t)h * S_LEN * HDD;
  int krow = tid >> 3, kc = (tid & 7) * 16;
  int vk = tid & 31, vd0 = (tid >> 5) * 16;
  int ntiles = (qbase >> 5) + 2;

  for (int t = 0; t < ntiles; ++t) {
    int kb0 = t * 32;
    __syncthreads();
    {
      const bf16x8* src = (const bf16x8*)(kp + (size_t)(kb0 + krow) * HDD + kc);
      bf16x8 x0 = src[0], x1 = src[1];
      *(bf16x8*)(Ksh + krow * 136 + kc) = x0;
      *(bf16x8*)(Ksh + krow * 136 + kc + 8) = x1;
      const bf16x8* vsrc = (const bf16x8*)(vp + (size_t)(kb0 + vk) * HDD + vd0);
      bf16x8 v0 = vsrc[0], v1 = vsrc[1];
#pragma unroll
      for (int j = 0; j < 8; ++j) {
        int d = vd0 + j;
        Vsh[d * 32 + (((vk >> 3) ^ (d & 3)) << 3) + (vk & 7)] = (u16)v0[j];
        int d2 = vd0 + 8 + j;
        Vsh[d2 * 32 + (((vk >> 3) ^ (d2 & 3)) << 3) + (vk & 7)] = (u16)v1[j];
      }
    }
    __syncthreads();

    f32x4 sa0 = z4, sa1 = z4;
#pragma unroll
    for (int d0 = 0; d0 < 4; ++d0) {
      bf16x8 k0 = *(const bf16x8*)(Ksh + lane15 * 136 + d0 * 32 + g * 8);
      bf16x8 k1 = *(const bf16x8*)(Ksh + (16 + lane15) * 136 + d0 * 32 + g * 8);
      sa0 = __builtin_amdgcn_mfma_f32_16x16x32_bf16(k0, qf[d0], sa0, 0, 0, 0);
      sa1 = __builtin_amdgcn_mfma_f32_16x16x32_bf16(k1, qf[d0], sa1, 0, 0, 0);
    }
    float s[8];
#pragma unroll
    for (int rr = 0; rr < 4; ++rr) {
      int kg0 = kb0 + 4 * g + rr;
      int kg1 = kb0 + 16 + 4 * g + rr;
      s[rr] = (kg0 > qrow) ? -1e30f : sa0[rr];
      s[4 + rr] = (kg1 > qrow) ? -1e30f : sa1[rr];
    }
    float mx = s[0];
#pragma unroll
    for (int i = 1; i < 8; ++i) mx = fmaxf(mx, s[i]);
    mx = fmaxf(mx, __shfl_xor(mx, 16));
    mx = fmaxf(mx, __shfl_xor(mx, 32));
    float mnew = fmaxf(m_run, mx);
    float fac = exp2f((m_run - mnew) * 1.4426950408889634f);
    float p[8], psum = 0.f;
#pragma unroll
    for (int i = 0; i < 8; ++i) {
      p[i] = exp2f((s[i] - mnew) * 1.4426950408889634f);
      psum += p[i];
    }
    psum += __shfl_xor(psum, 16);
    psum += __shfl_xor(psum, 32);
    l_run = l_run * fac + psum;
    m_run = mnew;
#pragma unroll
    for (int db = 0; db < 8; ++db) pv[db] *= fac;

    u32 w0 = (u32)f2bf(p[0]) | ((u32)f2bf(p[1]) << 16);
    u32 w1 = (u32)f2bf(p[2]) | ((u32)f2bf(p[3]) << 16);
    u32 w2 = (u32)f2bf(p[4]) | ((u32)f2bf(p[5]) << 16);
    u32 w3 = (u32)f2bf(p[6]) | ((u32)f2bf(p[7]) << 16);
    u32x2 pa, pb;
    pa.x = w0; pa.y = w1; pb.x = w2; pb.y = w3;
    *(u32x2*)(&Pt[w][lane15 * 40 + 4 * g]) = pa;
    *(u32x2*)(&Pt[w][lane15 * 40 + 16 + 4 * g]) = pb;
    asm volatile("s_waitcnt lgkmcnt(0)" ::: "memory");
    bf16x8 pfrag = *(const bf16x8*)(&Pt[w][lane15 * 40 + 8 * g]);

#pragma unroll
    for (int db = 0; db < 8; ++db) {
      int d = db * 16 + lane15;
      bf16x8 vf = *(const bf16x8*)(Vsh + d * 32 + ((g ^ (d & 3)) << 3));
      pv[db] = __builtin_amdgcn_mfma_f32_16x16x32_bf16(vf, pfrag, pv[db], 0, 0, 0);
    }
  }

  float inv = 1.0f / l_run;
#pragma unroll
  for (int db = 0; db < 8; ++db) {
    ushort4 o;
    o.x = f2bf(pv[db][0] * inv);
    o.y = f2bf(pv[db][1] * inv);
    o.z = f2bf(pv[db][2] * inv);
    o.w = f2bf(pv[db][3] * inv);
    *(ushort4*)(ctx + (size_t)qrow * HID + h * HDD + db * 16 + 4 * g) = o;
  }
}

// ---------------- launcher -------------------------------------------------
extern "C" void kernel_launch(void* const* d_in, const int* in_sizes, int n_in,
                              void* d_out, int out_size, void* d_ws, size_t ws_size,
                              hipStream_t stream) {
  const float* hidden = (const float*)d_in[0];
  const int* pid = (const int*)d_in[1];
  const float* wqkv = (const float*)d_in[3];
  const float* bqkv = (const float*)d_in[4];
  const float* wdense = (const float*)d_in[5];
  const float* bdense = (const float*)d_in[6];
  float* out = (float*)d_out;

  char* ws = (char*)d_ws;
  u16* W1 = (u16*)ws;
  u16* W2 = (u16*)(ws + 100663296);
  u16* X = (u16*)(ws + 134217728);
  u16* qb = (u16*)(ws + 150994944);
  u16* kbuf = (u16*)(ws + 167772160);
  u16* vbuf = (u16*)(ws + 184549376);
  u16* ctx = (u16*)(ws + 201326592);
  float* cos_t = (float*)(ws + 218103808);
  float* sin_t = (float*)(ws + 218365952);

  cvt_kernel<<<dim3(2048), dim3(256), 0, stream>>>(wqkv, W1, N_QKV * KDIM / 4);
  cvt_kernel<<<dim3(1024), dim3(256), 0, stream>>>(wdense, W2, HID * KDIM / 4);
  cvt_kernel<<<dim3(512), dim3(256), 0, stream>>>(hidden, X, S_LEN * HID / 4);
  tables_kernel<<<dim3(256), dim3(256), 0, stream>>>(cos_t, sin_t);

  gemm256<0><<<dim3(S_LEN / 256, N_QKV / 128), dim3(512), 0, stream>>>(
      X, W1, bqkv, N_QKV, qb, kbuf, vbuf, nullptr);

  rope_kernel<<<dim3(4096), dim3(256), 0, stream>>>(qb, kbuf, pid, cos_t, sin_t);

  attn_kernel<<<dim3(S_LEN / 64, NHEAD), dim3(256), 0, stream>>>(qb, kbuf, vbuf, ctx);

  gemm256<1><<<dim3(S_LEN / 256, HID / 128), dim3(512), 0, stream>>>(
      ctx, W2, bdense, HID, nullptr, nullptr, nullptr, out);
}

// Round 3
// 616.852 us; speedup vs baseline: 1.1069x; 1.0472x over previous
//
#include <hip/hip_runtime.h>

typedef unsigned short u16;
typedef unsigned int u32;
typedef __attribute__((ext_vector_type(4))) float f32x4;
typedef __attribute__((ext_vector_type(8))) short bf16x8;
typedef __attribute__((ext_vector_type(2))) unsigned int u32x2;

#define S_LEN 2048
#define NHEAD 32
#define HDD 128
#define HID 4096
#define N_QKV 12288
#define KDIM 4096
#define NT2 128  // K-tiles of BK=32

__device__ __forceinline__ u16 f2bf(float f) {
  u32 u = __builtin_bit_cast(u32, f);
  u = (u + 0x7FFFu + ((u >> 16) & 1u)) >> 16;
  return (u16)u;
}
__device__ __forceinline__ float bf2f(u16 h) {
  u32 u = ((u32)h) << 16;
  return __builtin_bit_cast(float, u);
}

__device__ __forceinline__ void gl2lds16(const void* g, void* l) {
  __builtin_amdgcn_global_load_lds(
      (const __attribute__((address_space(1))) u32*)g,
      (__attribute__((address_space(3))) u32*)l, 16, 0, 0);
}

// ---------------- fp32 -> bf16 conversion ----------------
__global__ __launch_bounds__(256) void cvt_kernel(const float* __restrict__ in,
                                                  u16* __restrict__ out, int n4) {
  int i = blockIdx.x * blockDim.x + threadIdx.x;
  int st = gridDim.x * blockDim.x;
  for (; i < n4; i += st) {
    float4 v = ((const float4*)in)[i];
    u32x2 o;
    o.x = (u32)f2bf(v.x) | ((u32)f2bf(v.y) << 16);
    o.y = (u32)f2bf(v.z) | ((u32)f2bf(v.w) << 16);
    ((u32x2*)out)[i] = o;
  }
}

// ---------------- RoPE tables: cos/sin [S][32] ----------------
__global__ __launch_bounds__(256) void tables_kernel(float* __restrict__ cos_t,
                                                     float* __restrict__ sin_t) {
  int idx = blockIdx.x * blockDim.x + threadIdx.x;
  if (idx >= S_LEN * 32) return;
  int s = idx >> 5, i = idx & 31;
  float invf = expf(-0.28782313662425572f * (float)i);
  float a = (float)s * invf;
  cos_t[idx] = cosf(a);
  sin_t[idx] = sinf(a);
}

// ---------------- 2D RoPE in-place on q/k (head-major [h][s][128]) -------
__global__ __launch_bounds__(256) void rope_kernel(u16* __restrict__ qb, u16* __restrict__ kb,
                                                   const int* __restrict__ pid,
                                                   const float* __restrict__ cos_t,
                                                   const float* __restrict__ sin_t) {
  int idx = blockIdx.x * blockDim.x + threadIdx.x;
  const int total = 2 * NHEAD * S_LEN * 64;
  int st = gridDim.x * blockDim.x;
  for (; idx < total; idx += st) {
    int i = idx & 31;
    int half = (idx >> 5) & 1;
    int s = (idx >> 6) & (S_LEN - 1);
    int h = (idx >> 17) & (NHEAD - 1);
    int qk = idx >> 22;
    int p = pid[half * S_LEN + s];
    float c = cos_t[p * 32 + i], sn = sin_t[p * 32 + i];
    u16* buf = qk ? kb : qb;
    int base = (h * S_LEN + s) * HDD + half * 64 + i;
    float x1 = bf2f(buf[base]), x2 = bf2f(buf[base + 32]);
    float o1 = x1 * c - x2 * sn;
    float o2 = x2 * c + x1 * sn;
    float sc = qk ? 1.0f : 0.08838834764831845f;
    buf[base] = f2bf(o1 * sc);
    buf[base + 32] = f2bf(o2 * sc);
  }
}

// ---------------- 256x256 bf16 GEMM, ring-4 LDS, counted vmcnt(8) --------
// C = A * B^T + bias.  A:[M][K] bf16, B:[N][K] bf16 (K contiguous).
// 512 threads = 8 waves (2M x 4N), per-wave 128x64 output, BK=32.
// LDS: 4 ring buffers x (A 16KB + B 16KB) = 128KB.
// Tile layout: paired-row 128B lines (line=row>>1), 16B-slot ^= (line&7).
// global_load_lds dest linear; SOURCE global addr inverse-swizzled (involution).
// Prefetch distance 3 tiles; per tile 2 phases of 16 MFMA; vmcnt(8) at tile
// boundary (2 tiles = 8 loads stay in flight; never drains to 0 mid-loop).
template <int EPI>
__global__ __launch_bounds__(512, 2) void gemm256(const u16* __restrict__ A,
                                                  const u16* __restrict__ B,
                                                  const float* __restrict__ bias, int N,
                                                  u16* __restrict__ qb, u16* __restrict__ kb,
                                                  u16* __restrict__ vb, float* __restrict__ outf) {
  __shared__ __align__(16) char lds[4][32768];

  const int tid = threadIdx.x;
  const int lane = tid & 63, w = tid >> 6;
  const int l15 = lane & 15, g = lane >> 4;
  const int wm = w >> 2, wn = w & 3;  // 2 x 4 wave grid

  // grid decode + bijective XCD swizzle (M always 8 tiles), M-fastest per chunk
  int perx = gridDim.x >> 3;  // blocks per XCD
  int npx = perx >> 3;        // N-panels per XCD
  int x = blockIdx.x & 7, loc = blockIdx.x >> 3;
  int mb = loc & 7, nb = x * npx + (loc >> 3);
  const int bm = mb * 256, bn = nb * 256;

  f32x4 acc[8][4];
  f32x4 z4 = {0.f, 0.f, 0.f, 0.f};
#pragma unroll
  for (int mi = 0; mi < 8; ++mi)
#pragma unroll
    for (int ni = 0; ni < 4; ++ni) acc[mi][ni] = z4;

  // ---- staging map: thread t, instr j covers LDS bytes (j*512+t)*16 of a
  // 16KB unit. line = idx>>3 (128B), phys slot = t&7; logical slot = phys ^
  // (line&7); row = 2*line + (slot_lin>>2); kbyte = (slot_lin&3)*16.
  int srow[2], skb[2];
#pragma unroll
  for (int j = 0; j < 2; ++j) {
    int idx = j * 512 + tid;
    int line = idx >> 3;
    int sl = (tid & 7) ^ (line & 7);
    srow[j] = 2 * line + (sl >> 2);
    skb[j] = (sl & 3) * 16;
  }
  const size_t K2 = (size_t)KDIM * 2;
  const char* gA0 = (const char*)A + (size_t)(bm + srow[0]) * K2 + skb[0];
  const char* gA1 = (const char*)A + (size_t)(bm + srow[1]) * K2 + skb[1];
  const char* gB0 = (const char*)B + (size_t)(bn + srow[0]) * K2 + skb[0];
  const char* gB1 = (const char*)B + (size_t)(bn + srow[1]) * K2 + skb[1];
  // LDS dest byte offsets (lane-independent; HW adds lane*16)
  const int dA0 = w * 1024, dA1 = 8192 + w * 1024;
  const int dB0 = 16384 + w * 1024, dB1 = 24576 + w * 1024;

#define ISSUE_A(t)                                   \
  {                                                  \
    char* Lb = (char*)lds[(t) & 3];                  \
    gl2lds16(gA0 + (size_t)(t) * 64, Lb + dA0);      \
    gl2lds16(gA1 + (size_t)(t) * 64, Lb + dA1);      \
  }
#define ISSUE_B(t)                                   \
  {                                                  \
    char* Lb = (char*)lds[(t) & 3];                  \
    gl2lds16(gB0 + (size_t)(t) * 64, Lb + dB0);      \
    gl2lds16(gB1 + (size_t)(t) * 64, Lb + dB1);      \
  }

  // ---- fragment ds_read byte offsets (swizzled), constant across tiles
  int offA[8], offB[4];
#pragma unroll
  for (int mi = 0; mi < 8; ++mi) {
    int r = wm * 128 + mi * 16 + l15;
    int line = r >> 1;
    int sl = (((r & 1) << 2) + g) ^ (line & 7);
    offA[mi] = line * 128 + sl * 16;
  }
#pragma unroll
  for (int ni = 0; ni < 4; ++ni) {
    int r = wn * 64 + ni * 16 + l15;
    int line = r >> 1;
    int sl = (((r & 1) << 2) + g) ^ (line & 7);
    offB[ni] = 16384 + line * 128 + sl * 16;
  }

  // ---- prologue: stage tiles 0,1,2 (12 loads); tile0 resident at vmcnt(8)
  ISSUE_A(0); ISSUE_B(0);
  ISSUE_A(1); ISSUE_B(1);
  ISSUE_A(2); ISSUE_B(2);
  asm volatile("s_waitcnt vmcnt(8)" ::: "memory");
  __builtin_amdgcn_s_barrier();

  for (int kt = 0; kt < NT2; ++kt) {
    const char* buf = lds[kt & 3];
    bf16x8 a[8], b[4];
    // ---- phase 1: frags (a0-a3, b0-b3) + stage A(kt+3)
#pragma unroll
    for (int mi = 0; mi < 4; ++mi) a[mi] = *(const bf16x8*)(buf + offA[mi]);
#pragma unroll
    for (int ni = 0; ni < 4; ++ni) b[ni] = *(const bf16x8*)(buf + offB[ni]);
    if (kt < NT2 - 3) ISSUE_A(kt + 3);
    __builtin_amdgcn_s_barrier();
    __builtin_amdgcn_s_setprio(1);
#pragma unroll
    for (int mi = 0; mi < 4; ++mi)
#pragma unroll
      for (int ni = 0; ni < 4; ++ni)
        acc[mi][ni] = __builtin_amdgcn_mfma_f32_16x16x32_bf16(a[mi], b[ni], acc[mi][ni], 0, 0, 0);
    __builtin_amdgcn_s_setprio(0);
    __builtin_amdgcn_s_barrier();
    // ---- phase 2: frags (a4-a7) + stage B(kt+3)
#pragma unroll
    for (int mi = 4; mi < 8; ++mi) a[mi] = *(const bf16x8*)(buf + offA[mi]);
    if (kt < NT2 - 3) ISSUE_B(kt + 3);
    __builtin_amdgcn_s_barrier();
    __builtin_amdgcn_s_setprio(1);
#pragma unroll
    for (int mi = 4; mi < 8; ++mi)
#pragma unroll
      for (int ni = 0; ni < 4; ++ni)
        acc[mi][ni] = __builtin_amdgcn_mfma_f32_16x16x32_bf16(a[mi], b[ni], acc[mi][ni], 0, 0, 0);
    __builtin_amdgcn_s_setprio(0);
    // ---- tile boundary: counted drain (tile kt+1 resident, 8 stay in flight)
    if (kt < NT2 - 3) {
      asm volatile("s_waitcnt vmcnt(8)" ::: "memory");
    } else if (kt == NT2 - 3) {
      asm volatile("s_waitcnt vmcnt(4)" ::: "memory");
    } else if (kt == NT2 - 2) {
      asm volatile("s_waitcnt vmcnt(0)" ::: "memory");
    }
    __builtin_amdgcn_s_barrier();
  }
#undef ISSUE_A
#undef ISSUE_B

  // ---- epilogue: D row(M) = 4*g + reg, col(N) = l15
#pragma unroll
  for (int ni = 0; ni < 4; ++ni) {
    int n = bn + wn * 64 + ni * 16 + l15;
    float bv = bias[n];
    if (EPI == 0) {
      int head = n / 384;
      int rem = n - head * 384;
      int part = rem >> 7;
      int d = rem & 127;
      u16* dst = (part == 0 ? qb : (part == 1 ? kb : vb)) + (size_t)head * S_LEN * HDD + d;
#pragma unroll
      for (int mi = 0; mi < 8; ++mi) {
        int m0 = bm + wm * 128 + mi * 16 + 4 * g;
#pragma unroll
        for (int rr = 0; rr < 4; ++rr) dst[(size_t)(m0 + rr) * HDD] = f2bf(acc[mi][ni][rr] + bv);
      }
    } else {
#pragma unroll
      for (int mi = 0; mi < 8; ++mi) {
        int m0 = bm + wm * 128 + mi * 16 + 4 * g;
#pragma unroll
        for (int rr = 0; rr < 4; ++rr) outf[(size_t)(m0 + rr) * N + n] = acc[mi][ni][rr] + bv;
      }
    }
  }
}

// ---------------- flash attention -----------------------------------------
__global__ __launch_bounds__(256) void attn_kernel(const u16* __restrict__ qb,
                                                   const u16* __restrict__ kb,
                                                   const u16* __restrict__ vb,
                                                   u16* __restrict__ ctx) {
  __shared__ __align__(16) u16 Ksh[32 * 136];
  __shared__ __align__(16) u16 Vsh[128 * 32];
  __shared__ __align__(16) u16 Pt[4][16 * 40];

  int tid = threadIdx.x;
  int lane = tid & 63, w = tid >> 6;
  int lane15 = lane & 15, g = lane >> 4;
  int h = blockIdx.y;
  int qbase = blockIdx.x * 64;
  int qrow = qbase + w * 16 + lane15;

  bf16x8 qf[4];
  const u16* qptr = qb + ((size_t)h * S_LEN + qrow) * HDD + g * 8;
#pragma unroll
  for (int d0 = 0; d0 < 4; ++d0) qf[d0] = *(const bf16x8*)(qptr + d0 * 32);

  f32x4 pv[8];
  f32x4 z4 = {0.f, 0.f, 0.f, 0.f};
#pragma unroll
  for (int db = 0; db < 8; ++db) pv[db] = z4;
  float m_run = -1e30f, l_run = 0.0f;

  const u16* kp = kb + (size_t)h * S_LEN * HDD;
  const u16* vp = vb + (size_t)h * S_LEN * HDD;
  int krow = tid >> 3, kc = (tid & 7) * 16;
  int vk = tid & 31, vd0 = (tid >> 5) * 16;
  int ntiles = (qbase >> 5) + 2;

  for (int t = 0; t < ntiles; ++t) {
    int kb0 = t * 32;
    __syncthreads();
    {
      const bf16x8* src = (const bf16x8*)(kp + (size_t)(kb0 + krow) * HDD + kc);
      bf16x8 x0 = src[0], x1 = src[1];
      *(bf16x8*)(Ksh + krow * 136 + kc) = x0;
      *(bf16x8*)(Ksh + krow * 136 + kc + 8) = x1;
      const bf16x8* vsrc = (const bf16x8*)(vp + (size_t)(kb0 + vk) * HDD + vd0);
      bf16x8 v0 = vsrc[0], v1 = vsrc[1];
#pragma unroll
      for (int j = 0; j < 8; ++j) {
        int d = vd0 + j;
        Vsh[d * 32 + (((vk >> 3) ^ (d & 3)) << 3) + (vk & 7)] = (u16)v0[j];
        int d2 = vd0 + 8 + j;
        Vsh[d2 * 32 + (((vk >> 3) ^ (d2 & 3)) << 3) + (vk & 7)] = (u16)v1[j];
      }
    }
    __syncthreads();

    f32x4 sa0 = z4, sa1 = z4;
#pragma unroll
    for (int d0 = 0; d0 < 4; ++d0) {
      bf16x8 k0 = *(const bf16x8*)(Ksh + lane15 * 136 + d0 * 32 + g * 8);
      bf16x8 k1 = *(const bf16x8*)(Ksh + (16 + lane15) * 136 + d0 * 32 + g * 8);
      sa0 = __builtin_amdgcn_mfma_f32_16x16x32_bf16(k0, qf[d0], sa0, 0, 0, 0);
      sa1 = __builtin_amdgcn_mfma_f32_16x16x32_bf16(k1, qf[d0], sa1, 0, 0, 0);
    }
    float s[8];
#pragma unroll
    for (int rr = 0; rr < 4; ++rr) {
      int kg0 = kb0 + 4 * g + rr;
      int kg1 = kb0 + 16 + 4 * g + rr;
      s[rr] = (kg0 > qrow) ? -1e30f : sa0[rr];
      s[4 + rr] = (kg1 > qrow) ? -1e30f : sa1[rr];
    }
    float mx = s[0];
#pragma unroll
    for (int i = 1; i < 8; ++i) mx = fmaxf(mx, s[i]);
    mx = fmaxf(mx, __shfl_xor(mx, 16));
    mx = fmaxf(mx, __shfl_xor(mx, 32));
    float mnew = fmaxf(m_run, mx);
    float fac = exp2f((m_run - mnew) * 1.4426950408889634f);
    float p[8], psum = 0.f;
#pragma unroll
    for (int i = 0; i < 8; ++i) {
      p[i] = exp2f((s[i] - mnew) * 1.4426950408889634f);
      psum += p[i];
    }
    psum += __shfl_xor(psum, 16);
    psum += __shfl_xor(psum, 32);
    l_run = l_run * fac + psum;
    m_run = mnew;
#pragma unroll
    for (int db = 0; db < 8; ++db) pv[db] *= fac;

    u32 w0 = (u32)f2bf(p[0]) | ((u32)f2bf(p[1]) << 16);
    u32 w1 = (u32)f2bf(p[2]) | ((u32)f2bf(p[3]) << 16);
    u32 w2 = (u32)f2bf(p[4]) | ((u32)f2bf(p[5]) << 16);
    u32 w3 = (u32)f2bf(p[6]) | ((u32)f2bf(p[7]) << 16);
    u32x2 pa, pb;
    pa.x = w0; pa.y = w1; pb.x = w2; pb.y = w3;
    *(u32x2*)(&Pt[w][lane15 * 40 + 4 * g]) = pa;
    *(u32x2*)(&Pt[w][lane15 * 40 + 16 + 4 * g]) = pb;
    asm volatile("s_waitcnt lgkmcnt(0)" ::: "memory");
    bf16x8 pfrag = *(const bf16x8*)(&Pt[w][lane15 * 40 + 8 * g]);

#pragma unroll
    for (int db = 0; db < 8; ++db) {
      int d = db * 16 + lane15;
      bf16x8 vf = *(const bf16x8*)(Vsh + d * 32 + ((g ^ (d & 3)) << 3));
      pv[db] = __builtin_amdgcn_mfma_f32_16x16x32_bf16(vf, pfrag, pv[db], 0, 0, 0);
    }
  }

  float inv = 1.0f / l_run;
#pragma unroll
  for (int db = 0; db < 8; ++db) {
    ushort4 o;
    o.x = f2bf(pv[db][0] * inv);
    o.y = f2bf(pv[db][1] * inv);
    o.z = f2bf(pv[db][2] * inv);
    o.w = f2bf(pv[db][3] * inv);
    *(ushort4*)(ctx + (size_t)qrow * HID + h * HDD + db * 16 + 4 * g) = o;
  }
}

// ---------------- launcher -------------------------------------------------
extern "C" void kernel_launch(void* const* d_in, const int* in_sizes, int n_in,
                              void* d_out, int out_size, void* d_ws, size_t ws_size,
                              hipStream_t stream) {
  const float* hidden = (const float*)d_in[0];
  const int* pid = (const int*)d_in[1];
  const float* wqkv = (const float*)d_in[3];
  const float* bqkv = (const float*)d_in[4];
  const float* wdense = (const float*)d_in[5];
  const float* bdense = (const float*)d_in[6];
  float* out = (float*)d_out;

  char* ws = (char*)d_ws;
  u16* W1 = (u16*)ws;
  u16* W2 = (u16*)(ws + 100663296);
  u16* X = (u16*)(ws + 134217728);
  u16* qb = (u16*)(ws + 150994944);
  u16* kbuf = (u16*)(ws + 167772160);
  u16* vbuf = (u16*)(ws + 184549376);
  u16* ctx = (u16*)(ws + 201326592);
  float* cos_t = (float*)(ws + 218103808);
  float* sin_t = (float*)(ws + 218365952);

  cvt_kernel<<<dim3(2048), dim3(256), 0, stream>>>(wqkv, W1, N_QKV * KDIM / 4);
  cvt_kernel<<<dim3(1024), dim3(256), 0, stream>>>(wdense, W2, HID * KDIM / 4);
  cvt_kernel<<<dim3(512), dim3(256), 0, stream>>>(hidden, X, S_LEN * HID / 4);
  tables_kernel<<<dim3(256), dim3(256), 0, stream>>>(cos_t, sin_t);

  // QKV: 8 M-tiles x 48 N-panels = 384 blocks (XCD-swizzled inside)
  gemm256<0><<<dim3(384), dim3(512), 0, stream>>>(
      X, W1, bqkv, N_QKV, qb, kbuf, vbuf, nullptr);

  rope_kernel<<<dim3(4096), dim3(256), 0, stream>>>(qb, kbuf, pid, cos_t, sin_t);

  attn_kernel<<<dim3(S_LEN / 64, NHEAD), dim3(256), 0, stream>>>(qb, kbuf, vbuf, ctx);

  // dense: 8 M-tiles x 16 N-panels = 128 blocks
  gemm256<1><<<dim3(128), dim3(512), 0, stream>>>(
      ctx, W2, bdense, HID, nullptr, nullptr, nullptr, out);
}

// Round 4
// 606.412 us; speedup vs baseline: 1.1260x; 1.0172x over previous
//
#include <hip/hip_runtime.h>

typedef unsigned short u16;
typedef unsigned int u32;
typedef __attribute__((ext_vector_type(4))) float f32x4;
typedef __attribute__((ext_vector_type(8))) short bf16x8;
typedef __attribute__((ext_vector_type(2))) unsigned int u32x2;

#define S_LEN 2048
#define NHEAD 32
#define HDD 128
#define HID 4096
#define N_QKV 12288
#define KDIM 4096
#define RS 12288  // mixed row stride (elements)

__device__ __forceinline__ u16 f2bf(float f) {
  u32 u = __builtin_bit_cast(u32, f);
  u = (u + 0x7FFFu + ((u >> 16) & 1u)) >> 16;
  return (u16)u;
}
__device__ __forceinline__ float bf2f(u16 h) {
  u32 u = ((u32)h) << 16;
  return __builtin_bit_cast(float, u);
}

__device__ __forceinline__ void gl2lds16(const void* g, void* l) {
  __builtin_amdgcn_global_load_lds(
      (const __attribute__((address_space(1))) u32*)g,
      (__attribute__((address_space(3))) u32*)l, 16, 0, 0);
}

// ---------------- fp32 -> bf16 conversion ----------------
__global__ __launch_bounds__(256) void cvt_kernel(const float* __restrict__ in,
                                                  u16* __restrict__ out, int n4) {
  int i = blockIdx.x * blockDim.x + threadIdx.x;
  int st = gridDim.x * blockDim.x;
  for (; i < n4; i += st) {
    float4 v = ((const float4*)in)[i];
    u32x2 o;
    o.x = (u32)f2bf(v.x) | ((u32)f2bf(v.y) << 16);
    o.y = (u32)f2bf(v.z) | ((u32)f2bf(v.w) << 16);
    ((u32x2*)out)[i] = o;
  }
}

// ---------------- RoPE tables: cos/sin [S][32] ----------------
__global__ __launch_bounds__(256) void tables_kernel(float* __restrict__ cos_t,
                                                     float* __restrict__ sin_t) {
  int idx = blockIdx.x * blockDim.x + threadIdx.x;
  if (idx >= S_LEN * 32) return;
  int s = idx >> 5, i = idx & 31;
  float invf = expf(-0.28782313662425572f * (float)i);
  float a = (float)s * invf;
  cos_t[idx] = cosf(a);
  sin_t[idx] = sinf(a);
}

// ---------------- 2D RoPE in-place on mixed [s][12288] --------------------
__global__ __launch_bounds__(256) void rope_kernel(u16* __restrict__ mixed,
                                                   const int* __restrict__ pid,
                                                   const float* __restrict__ cos_t,
                                                   const float* __restrict__ sin_t) {
  int idx = blockIdx.x * blockDim.x + threadIdx.x;
  const int total = 2 * NHEAD * S_LEN * 2 * 8;  // 2^21
  if (idx >= total) return;
  int j = idx & 7;
  int half = (idx >> 3) & 1;
  int s = (idx >> 4) & (S_LEN - 1);
  int h = (idx >> 15) & (NHEAD - 1);
  int qk = idx >> 20;
  int i0 = j * 4;
  int p = pid[half * S_LEN + s];
  float4 c4 = *(const float4*)(cos_t + p * 32 + i0);
  float4 s4 = *(const float4*)(sin_t + p * 32 + i0);
  u16* base = mixed + (size_t)s * RS + h * 384 + qk * 128 + half * 64 + i0;
  ushort4 x1v = *(const ushort4*)(base);
  ushort4 x2v = *(const ushort4*)(base + 32);
  float sc = qk ? 1.0f : 0.08838834764831845f;
  ushort4 o1, o2;
  {
    float x1 = bf2f(x1v.x), x2 = bf2f(x2v.x);
    o1.x = f2bf((x1 * c4.x - x2 * s4.x) * sc);
    o2.x = f2bf((x2 * c4.x + x1 * s4.x) * sc);
  }
  {
    float x1 = bf2f(x1v.y), x2 = bf2f(x2v.y);
    o1.y = f2bf((x1 * c4.y - x2 * s4.y) * sc);
    o2.y = f2bf((x2 * c4.y + x1 * s4.y) * sc);
  }
  {
    float x1 = bf2f(x1v.z), x2 = bf2f(x2v.z);
    o1.z = f2bf((x1 * c4.z - x2 * s4.z) * sc);
    o2.z = f2bf((x2 * c4.z + x1 * s4.z) * sc);
  }
  {
    float x1 = bf2f(x1v.w), x2 = bf2f(x2v.w);
    o1.w = f2bf((x1 * c4.w - x2 * s4.w) * sc);
    o2.w = f2bf((x2 * c4.w + x1 * s4.w) * sc);
  }
  *(ushort4*)(base) = o1;
  *(ushort4*)(base + 32) = o2;
}

// ---------------- 256x256 bf16 GEMM, m201-style schedule ------------------
template <int EPI>
__global__ __launch_bounds__(512, 2) void gemm256(const u16* __restrict__ A,
                                                  const u16* __restrict__ B,
                                                  const float* __restrict__ bias, int N,
                                                  int NTt,
                                                  u16* __restrict__ outb, float* __restrict__ outf) {
  __shared__ __align__(16) char lds[2][65536];  // per buf: A0|A1|B0|B1 16KB units

  const int tid = threadIdx.x;
  const int lane = tid & 63, w = tid >> 6;
  const int l15 = lane & 15, g = lane >> 4;
  const int wm = w >> 2, wn = w & 3;

  int perx = gridDim.x >> 3;
  int npx = perx >> 3;
  int x = blockIdx.x & 7, loc = blockIdx.x >> 3;
  int mb = loc & 7, nb = x * npx + (loc >> 3);
  const int bm = mb * 256, bn = nb * 256;

  f32x4 acc[8][4];
  f32x4 z4 = {0.f, 0.f, 0.f, 0.f};
#pragma unroll
  for (int mi = 0; mi < 8; ++mi)
#pragma unroll
    for (int ni = 0; ni < 4; ++ni) acc[mi][ni] = z4;

  int srow[2], skb[2];
#pragma unroll
  for (int j = 0; j < 2; ++j) {
    int slot = j * 512 + tid;
    int line = slot >> 3;
    int sl = (slot & 7) ^ (line & 7);
    srow[j] = 2 * line + (sl >> 2);
    skb[j] = (sl & 3) * 16;
  }
  const size_t K2 = (size_t)KDIM * 2;
  const char* gA[2];
  const char* gB[2];
#pragma unroll
  for (int j = 0; j < 2; ++j) {
    gA[j] = (const char*)A + (size_t)(bm + srow[j]) * K2 + skb[j];
    gB[j] = (const char*)B + (size_t)(bn + srow[j]) * K2 + skb[j];
  }
  const int ldst = w * 1024;

#define ISSUE_U(buf, isA, kk, kt)                                              \
  {                                                                            \
    char* Lb = lds[(buf)] + ((isA) ? 0 : 32768) + (kk) * 16384;                \
    const char* g0 = (isA) ? gA[0] : gB[0];                                    \
    const char* g1 = (isA) ? gA[1] : gB[1];                                    \
    size_t ko = (size_t)(kt) * 128 + (size_t)(kk) * 64;                        \
    gl2lds16(g0 + ko, Lb + ldst);                                              \
    gl2lds16(g1 + ko, Lb + 8192 + ldst);                                       \
  }

  int offA[8], offB[4];
#pragma unroll
  for (int mi = 0; mi < 8; ++mi) {
    int r = wm * 128 + mi * 16 + l15;
    int line = r >> 1;
    int sl = (((r & 1) << 2) + g) ^ (line & 7);
    offA[mi] = line * 128 + sl * 16;
  }
#pragma unroll
  for (int ni = 0; ni < 4; ++ni) {
    int r = wn * 64 + ni * 16 + l15;
    int line = r >> 1;
    int sl = (((r & 1) << 2) + g) ^ (line & 7);
    offB[ni] = 32768 + line * 128 + sl * 16;
  }

  ISSUE_U(0, 1, 0, 0);
  ISSUE_U(0, 0, 0, 0);
  ISSUE_U(0, 1, 1, 0);
  ISSUE_U(0, 0, 1, 0);
  asm volatile("s_waitcnt vmcnt(4)" ::: "memory");
  __builtin_amdgcn_s_barrier();
  asm volatile("" ::: "memory");

  bf16x8 a_[4], a2_[4], b_[4];
  for (int kt = 0; kt < NTt; ++kt) {
    const char* buf = lds[kt & 1];
    const int nbuf = (kt + 1) & 1;
    const bool pf = (kt + 1) < NTt;
    // ph0: kk0, mh0
#pragma unroll
    for (int mi = 0; mi < 4; ++mi) a_[mi] = *(const bf16x8*)(buf + offA[mi]);
#pragma unroll
    for (int ni = 0; ni < 4; ++ni) b_[ni] = *(const bf16x8*)(buf + offB[ni]);
    if (pf) ISSUE_U(nbuf, 1, 0, kt + 1);
    asm volatile("" ::: "memory");
    __builtin_amdgcn_s_barrier();
    asm volatile("" ::: "memory");
    __builtin_amdgcn_s_setprio(1);
#pragma unroll
    for (int mi = 0; mi < 4; ++mi)
#pragma unroll
      for (int ni = 0; ni < 4; ++ni)
        acc[mi][ni] = __builtin_amdgcn_mfma_f32_16x16x32_bf16(a_[mi], b_[ni], acc[mi][ni], 0, 0, 0);
    __builtin_amdgcn_s_setprio(0);
    // ph1: kk0, mh1
#pragma unroll
    for (int mi = 0; mi < 4; ++mi) a2_[mi] = *(const bf16x8*)(buf + offA[4 + mi]);
    if (pf) ISSUE_U(nbuf, 0, 0, kt + 1);
    if (pf)
      asm volatile("s_waitcnt vmcnt(4)" ::: "memory");
    else
      asm volatile("s_waitcnt vmcnt(0)" ::: "memory");
    __builtin_amdgcn_s_barrier();
    asm volatile("" ::: "memory");
    __builtin_amdgcn_s_setprio(1);
#pragma unroll
    for (int mi = 0; mi < 4; ++mi)
#pragma unroll
      for (int ni = 0; ni < 4; ++ni)
        acc[4 + mi][ni] = __builtin_amdgcn_mfma_f32_16x16x32_bf16(a2_[mi], b_[ni], acc[4 + mi][ni], 0, 0, 0);
    __builtin_amdgcn_s_setprio(0);
    // ph2: kk1, mh0
#pragma unroll
    for (int mi = 0; mi < 4; ++mi) a_[mi] = *(const bf16x8*)(buf + 16384 + offA[mi]);
#pragma unroll
    for (int ni = 0; ni < 4; ++ni) b_[ni] = *(const bf16x8*)(buf + 16384 + offB[ni]);
    if (pf) ISSUE_U(nbuf, 1, 1, kt + 1);
    asm volatile("" ::: "memory");
    __builtin_amdgcn_s_barrier();
    asm volatile("" ::: "memory");
    __builtin_amdgcn_s_setprio(1);
#pragma unroll
    for (int mi = 0; mi < 4; ++mi)
#pragma unroll
      for (int ni = 0; ni < 4; ++ni)
        acc[mi][ni] = __builtin_amdgcn_mfma_f32_16x16x32_bf16(a_[mi], b_[ni], acc[mi][ni], 0, 0, 0);
    __builtin_amdgcn_s_setprio(0);
    // ph3: kk1, mh1
#pragma unroll
    for (int mi = 0; mi < 4; ++mi) a2_[mi] = *(const bf16x8*)(buf + 16384 + offA[4 + mi]);
    if (pf) ISSUE_U(nbuf, 0, 1, kt + 1);
    if (pf) asm volatile("s_waitcnt vmcnt(4)" ::: "memory");
    __builtin_amdgcn_s_barrier();
    asm volatile("" ::: "memory");
    __builtin_amdgcn_s_setprio(1);
#pragma unroll
    for (int mi = 0; mi < 4; ++mi)
#pragma unroll
      for (int ni = 0; ni < 4; ++ni)
        acc[4 + mi][ni] = __builtin_amdgcn_mfma_f32_16x16x32_bf16(a2_[mi], b_[ni], acc[4 + mi][ni], 0, 0, 0);
    __builtin_amdgcn_s_setprio(0);
  }
#undef ISSUE_U

#pragma unroll
  for (int ni = 0; ni < 4; ++ni) {
    int n = bn + wn * 64 + ni * 16 + l15;
    if (EPI == 0) {
      float bv = bias[n];
#pragma unroll
      for (int mi = 0; mi < 8; ++mi) {
        int m0 = bm + wm * 128 + mi * 16 + 4 * g;
#pragma unroll
        for (int rr = 0; rr < 4; ++rr)
          outb[(size_t)(m0 + rr) * N + n] = f2bf(acc[mi][ni][rr] + bv);
      }
    } else {
#pragma unroll
      for (int mi = 0; mi < 8; ++mi) {
        int m0 = bm + wm * 128 + mi * 16 + 4 * g;
#pragma unroll
        for (int rr = 0; rr < 4; ++rr) outf[(size_t)(m0 + rr) * N + n] = acc[mi][ni][rr];
      }
    }
  }
}

// ---------------- split-K reduce: out = P0 + P1 + bias --------------------
__global__ __launch_bounds__(256) void reduce_kernel(const float* __restrict__ P0,
                                                     const float* __restrict__ P1,
                                                     const float* __restrict__ bias,
                                                     float* __restrict__ out, int n4) {
  int i = blockIdx.x * blockDim.x + threadIdx.x;
  int st = gridDim.x * blockDim.x;
  for (; i < n4; i += st) {
    float4 a = ((const float4*)P0)[i];
    float4 b = ((const float4*)P1)[i];
    float4 bv = *(const float4*)(bias + ((i * 4) & (HID - 1)));
    float4 o;
    o.x = a.x + b.x + bv.x;
    o.y = a.y + b.y + bv.y;
    o.z = a.z + b.z + bv.z;
    o.w = a.w + b.w + bv.w;
    ((float4*)out)[i] = o;
  }
}

// ---------------- flash attention (reads mixed layout) --------------------
__global__ __launch_bounds__(256) void attn_kernel(const u16* __restrict__ mixed,
                                                   u16* __restrict__ ctx) {
  __shared__ __align__(16) u16 Ksh[32 * 136];
  __shared__ __align__(16) u16 Vsh[128 * 32];
  __shared__ __align__(16) u16 Pt[4][16 * 40];

  int tid = threadIdx.x;
  int lane = tid & 63, w = tid >> 6;
  int lane15 = lane & 15, g = lane >> 4;
  int h = blockIdx.y;
  int qbase = blockIdx.x * 64;
  int qrow = qbase + w * 16 + lane15;

  const u16* qp = mixed + (size_t)h * 384;
  const u16* kp = mixed + (size_t)h * 384 + 128;
  const u16* vp = mixed + (size_t)h * 384 + 256;

  bf16x8 qf[4];
  const u16* qptr = qp + (size_t)qrow * RS + g * 8;
#pragma unroll
  for (int d0 = 0; d0 < 4; ++d0) qf[d0] = *(const bf16x8*)(qptr + d0 * 32);

  f32x4 pv[8];
  f32x4 z4 = {0.f, 0.f, 0.f, 0.f};
#pragma unroll
  for (int db = 0; db < 8; ++db) pv[db] = z4;
  float m_run = -1e30f, l_run = 0.0f;

  int krow = tid >> 3, kc = (tid & 7) * 16;
  int a_ = tid & 15, b_ = tid >> 4;
  int ntiles = (qbase >> 5) + 2;

  for (int t = 0; t < ntiles; ++t) {
    int kb0 = t * 32;
    __syncthreads();
    {
      const bf16x8* src = (const bf16x8*)(kp + (size_t)(kb0 + krow) * RS + kc);
      bf16x8 x0 = src[0], x1 = src[1];
      *(bf16x8*)(Ksh + krow * 136 + kc) = x0;
      *(bf16x8*)(Ksh + krow * 136 + kc + 8) = x1;
      int k0 = 2 * a_, d0 = 8 * b_;
      bf16x8 r0 = *(const bf16x8*)(vp + (size_t)(kb0 + k0) * RS + d0);
      bf16x8 r1 = *(const bf16x8*)(vp + (size_t)(kb0 + k0 + 1) * RS + d0);
#pragma unroll
      for (int jj = 0; jj < 8; ++jj) {
        int d = d0 + jj;
        u32 val = (u32)(u16)r0[jj] | ((u32)(u16)r1[jj] << 16);
        *(u32*)(Vsh + d * 32 + (((k0 >> 3) ^ (d & 3)) << 3) + (k0 & 7)) = val;
      }
    }
    __syncthreads();

    f32x4 sa0 = z4, sa1 = z4;
#pragma unroll
    for (int d0 = 0; d0 < 4; ++d0) {
      bf16x8 k0f = *(const bf16x8*)(Ksh + lane15 * 136 + d0 * 32 + g * 8);
      bf16x8 k1f = *(const bf16x8*)(Ksh + (16 + lane15) * 136 + d0 * 32 + g * 8);
      sa0 = __builtin_amdgcn_mfma_f32_16x16x32_bf16(k0f, qf[d0], sa0, 0, 0, 0);
      sa1 = __builtin_amdgcn_mfma_f32_16x16x32_bf16(k1f, qf[d0], sa1, 0, 0, 0);
    }
    float s[8];
#pragma unroll
    for (int rr = 0; rr < 4; ++rr) {
      int kg0 = kb0 + 4 * g + rr;
      int kg1 = kb0 + 16 + 4 * g + rr;
      s[rr] = (kg0 > qrow) ? -1e30f : sa0[rr];
      s[4 + rr] = (kg1 > qrow) ? -1e30f : sa1[rr];
    }
    float mx = s[0];
#pragma unroll
    for (int i = 1; i < 8; ++i) mx = fmaxf(mx, s[i]);
    mx = fmaxf(mx, __shfl_xor(mx, 16));
    mx = fmaxf(mx, __shfl_xor(mx, 32));
    float mnew = fmaxf(m_run, mx);
    float fac = exp2f((m_run - mnew) * 1.4426950408889634f);
    float p[8], psum = 0.f;
#pragma unroll
    for (int i = 0; i < 8; ++i) {
      p[i] = exp2f((s[i] - mnew) * 1.4426950408889634f);
      psum += p[i];
    }
    psum += __shfl_xor(psum, 16);
    psum += __shfl_xor(psum, 32);
    l_run = l_run * fac + psum;
    m_run = mnew;
#pragma unroll
    for (int db = 0; db < 8; ++db) pv[db] *= fac;

    u32 w0 = (u32)f2bf(p[0]) | ((u32)f2bf(p[1]) << 16);
    u32 w1 = (u32)f2bf(p[2]) | ((u32)f2bf(p[3]) << 16);
    u32 w2 = (u32)f2bf(p[4]) | ((u32)f2bf(p[5]) << 16);
    u32 w3 = (u32)f2bf(p[6]) | ((u32)f2bf(p[7]) << 16);
    u32x2 pa, pb;
    pa.x = w0; pa.y = w1; pb.x = w2; pb.y = w3;
    *(u32x2*)(&Pt[w][lane15 * 40 + 4 * g]) = pa;
    *(u32x2*)(&Pt[w][lane15 * 40 + 16 + 4 * g]) = pb;
    asm volatile("s_waitcnt lgkmcnt(0)" ::: "memory");
    bf16x8 pfrag = *(const bf16x8*)(&Pt[w][lane15 * 40 + 8 * g]);

#pragma unroll
    for (int db = 0; db < 8; ++db) {
      int d = db * 16 + lane15;
      bf16x8 vf = *(const bf16x8*)(Vsh + d * 32 + ((g ^ (d & 3)) << 3));
      pv[db] = __builtin_amdgcn_mfma_f32_16x16x32_bf16(vf, pfrag, pv[db], 0, 0, 0);
    }
  }

  float inv = 1.0f / l_run;
#pragma unroll
  for (int db = 0; db < 8; ++db) {
    ushort4 o;
    o.x = f2bf(pv[db][0] * inv);
    o.y = f2bf(pv[db][1] * inv);
    o.z = f2bf(pv[db][2] * inv);
    o.w = f2bf(pv[db][3] * inv);
    *(ushort4*)(ctx + (size_t)qrow * HID + h * HDD + db * 16 + 4 * g) = o;
  }
}

// ---------------- launcher -------------------------------------------------
extern "C" void kernel_launch(void* const* d_in, const int* in_sizes, int n_in,
                              void* d_out, int out_size, void* d_ws, size_t ws_size,
                              hipStream_t stream) {
  const float* hidden = (const float*)d_in[0];
  const int* pid = (const int*)d_in[1];
  const float* wqkv = (const float*)d_in[3];
  const float* bqkv = (const float*)d_in[4];
  const float* wdense = (const float*)d_in[5];
  const float* bdense = (const float*)d_in[6];
  float* out = (float*)d_out;

  char* ws = (char*)d_ws;
  u16* W1 = (u16*)ws;
  u16* W2 = (u16*)(ws + 100663296);
  u16* X = (u16*)(ws + 134217728);
  u16* mixed = (u16*)(ws + 150994944);
  u16* ctx = (u16*)(ws + 201326592);
  float* cos_t = (float*)(ws + 218103808);
  float* sin_t = (float*)(ws + 218365952);
  float* P0 = (float*)ws;                  // reuse W1 region (dead after QKV gemm)
  float* P1 = (float*)(ws + 33554432);

  cvt_kernel<<<dim3(2048), dim3(256), 0, stream>>>(wqkv, W1, N_QKV * KDIM / 4);
  cvt_kernel<<<dim3(1024), dim3(256), 0, stream>>>(wdense, W2, HID * KDIM / 4);
  cvt_kernel<<<dim3(512), dim3(256), 0, stream>>>(hidden, X, S_LEN * HID / 4);
  tables_kernel<<<dim3(256), dim3(256), 0, stream>>>(cos_t, sin_t);

  gemm256<0><<<dim3(384), dim3(512), 0, stream>>>(
      X, W1, bqkv, N_QKV, 64, mixed, nullptr);

  rope_kernel<<<dim3(8192), dim3(256), 0, stream>>>(mixed, pid, cos_t, sin_t);

  attn_kernel<<<dim3(S_LEN / 64, NHEAD), dim3(256), 0, stream>>>(mixed, ctx);

  // dense split-K x2: K offset via pointer (row stride K2 compile-time)
  gemm256<1><<<dim3(128), dim3(512), 0, stream>>>(
      ctx, W2, nullptr, HID, 32, nullptr, P0);
  gemm256<1><<<dim3(128), dim3(512), 0, stream>>>(
      ctx + 2048, W2 + 2048, nullptr, HID, 32, nullptr, P1);

  reduce_kernel<<<dim3(2048), dim3(256), 0, stream>>>(
      P0, P1, bdense, out, S_LEN * HID / 4);
}